// Round 5
// baseline (376.111 us; speedup 1.0000x reference)
//
#include <hip/hip_runtime.h>

#define FEAT 128

typedef __attribute__((ext_vector_type(8))) short short8;
typedef __attribute__((ext_vector_type(4))) float floatx4;

// bf16 helpers (manual, RNE) — finite data only.
__device__ __forceinline__ unsigned short f2bf(float f) {
    unsigned int u = __float_as_uint(f);
    u += 0x7fffu + ((u >> 16) & 1u);
    return (unsigned short)(u >> 16);
}
__device__ __forceinline__ float bf_lo(unsigned int u) { return __uint_as_float(u << 16); }
__device__ __forceinline__ float bf_hi(unsigned int u) { return __uint_as_float(u & 0xffff0000u); }
__device__ __forceinline__ unsigned int pack2(float a, float b) {
    return (unsigned int)f2bf(a) | ((unsigned int)f2bf(b) << 16);
}

// ===========================================================================
// Fused convert + histogram + W-prep:
//  blocks [0, chB): stream x -> bf16 while issuing dst-histogram atomics
//  blocks chB, chB+1: repack W1/W2 into MFMA fragment order.
// ===========================================================================
__global__ __launch_bounds__(256) void convert_hist_prep(
        const float* __restrict__ x, unsigned short* __restrict__ xb, long n4,
        const int* __restrict__ dst, int* __restrict__ counts, int E,
        const float* __restrict__ W1, const float* __restrict__ W2,
        unsigned short* __restrict__ bfW1, unsigned short* __restrict__ bfW2,
        int chB) {
    const int t = threadIdx.x;
    if (blockIdx.x >= chB) {
        // bfW[((kc*8+ct)*64+lane)*8+j] = bf16(W[kc*32+(lane>>4)*8+j][ct*16+(lane&15)])
        const int wsel = blockIdx.x - chB;
        const float* W = wsel ? W2 : W1;
        unsigned short* bfW = wsel ? bfW2 : bfW1;
#pragma unroll
        for (int it = 0; it < 8; it++) {
            const int idx = it * 256 + t;
            const int kc = idx >> 9;
            const int ct = (idx >> 6) & 7;
            const int lane = idx & 63;
            const int quad = lane >> 4;
            const int n = ct * 16 + (lane & 15);
            unsigned short frag[8];
#pragma unroll
            for (int j = 0; j < 8; j++)
                frag[j] = f2bf(W[(kc * 32 + quad * 8 + j) * FEAT + n]);
            *(uint4*)&bfW[(long)idx * 8] = *(uint4*)frag;
        }
        return;
    }
    const long i = (long)blockIdx.x * 256 + t;
    if (i < E) atomicAdd(&counts[dst[i]], 1);
    if (i < n4) {
        const float4 v = *(const float4*)&x[i * 4];
        uint2 p;
        p.x = pack2(v.x, v.y);
        p.y = pack2(v.z, v.w);
        *(uint2*)&xb[i * 4] = p;
    }
}

// ===========================================================================
// Exclusive scan level 1: 256 threads x 4 elems = 1024-chunk per block.
// ===========================================================================
__global__ __launch_bounds__(256) void scan_chunk(const int* __restrict__ counts,
                                                  int* __restrict__ offsets,
                                                  int* __restrict__ blocksums, int N) {
    const int t = threadIdx.x;
    const int base = blockIdx.x * 1024 + t * 4;
    int c0 = (base + 0 < N) ? counts[base + 0] : 0;
    int c1 = (base + 1 < N) ? counts[base + 1] : 0;
    int c2 = (base + 2 < N) ? counts[base + 2] : 0;
    int c3 = (base + 3 < N) ? counts[base + 3] : 0;
    const int sum = c0 + c1 + c2 + c3;

    const int lane = t & 63, wv = t >> 6;
    int v = sum;
#pragma unroll
    for (int off = 1; off < 64; off <<= 1) {
        int n = __shfl_up(v, off);
        if (lane >= off) v += n;
    }
    __shared__ int ws[4];
    if (lane == 63) ws[wv] = v;
    __syncthreads();
    int wp = 0;
    for (int w = 0; w < wv; w++) wp += ws[w];
    int excl = wp + v - sum;

    if (base + 0 < N) offsets[base + 0] = excl;
    if (base + 1 < N) offsets[base + 1] = excl + c0;
    if (base + 2 < N) offsets[base + 2] = excl + c0 + c1;
    if (base + 3 < N) offsets[base + 3] = excl + c0 + c1 + c2;
    if (t == 255) blocksums[blockIdx.x] = wp + v;
}

// ===========================================================================
// Scan level 2 fused into add_base: each block re-derives prefix of
// blocksums[0..c) with wave 0, adds it, duplicates into cursor, caps
// offsets[N] = E.
// ===========================================================================
__global__ __launch_bounds__(256) void add_base(int* __restrict__ offsets,
                                                int* __restrict__ cursor,
                                                const int* __restrict__ blocksums,
                                                int N, int E) {
    __shared__ int sbase;
    const int c = blockIdx.x >> 2;       // this block's chunk id
    const int t = threadIdx.x;
    if (t < 64) {
        int s = 0;
        for (int j = t; j < c; j += 64) s += blocksums[j];
#pragma unroll
        for (int off = 32; off; off >>= 1) s += __shfl_down(s, off);
        if (t == 0) sbase = s;
    }
    __syncthreads();
    const int base = sbase;
    const int i = blockIdx.x * 256 + t;
    if (i < N) {
        const int off = offsets[i] + base;
        offsets[i] = off;
        cursor[i] = off;
    }
    if (i == 0) offsets[N] = E;
}

// Permute writes (src, dst) pairs so the gather kernel can stream them.
__global__ __launch_bounds__(256) void permute_kernel(const int* __restrict__ src,
                                                      const int* __restrict__ dst,
                                                      int* __restrict__ cursor,
                                                      int2* __restrict__ sorted_ed, int E) {
    const int e = blockIdx.x * 256 + threadIdx.x;
    if (e < E) {
        const int d = dst[e];
        const int pos = atomicAdd(&cursor[d], 1);
        sorted_ed[pos] = make_int2(src[e], d);
    }
}

// ===========================================================================
// FUSED gather + MFMA GEMM, round-5 redesign (edge-stream + LDS accum):
//   out_rows[i] = (sum_{e in CSR(i)} h[sorted[e]]) @ W + bias  [opt ReLU]
//
// A 256-thread block owns 64 nodes = one CONTIGUOUS range of dst-sorted
// edges. 16 threads per edge: lane f loads uint4 f of the 256 B row — one
// dwordx4 instruction covers the row as 2 full 128 B lines (vs 4x64 B
// requests in the per-column design). Each 16-lane group walks a contiguous
// 1/16 sub-chunk, accumulating REGISTER RUNS (dst-sorted => avg-6.25-edge
// runs) and flushing a run with 8 ds_add_f32 into the 64x128 f32 LDS tile.
// Edge loads are batched x4 with no control-flow feedback — nothing for the
// scheduler to re-serialize (r1/r2/r4 lesson). Zero padded slots (old
// per-column loop: 39% slot efficiency). LDS XOR-swizzle ((node&7)<<2 on
// the word index) breaks the stride-512B bank conflict at fragment reads.
// MFMA phase: wave w reads A-frags for local nodes w*16..w*16+15 from LDS;
// B-frags from frag-ordered bfW in global (L1/L2-hot 32 KB).
// ===========================================================================
template <bool RELU, bool OUT_BF16>
__global__ __launch_bounds__(256) void gather_gemm(const unsigned short* __restrict__ h,
                                                   const int* __restrict__ offsets,
                                                   const int2* __restrict__ sorted_ed,
                                                   const unsigned short* __restrict__ bfW,
                                                   const float* __restrict__ bias,
                                                   void* __restrict__ out, int N) {
    __shared__ float lacc[64 * FEAT];            // 32 KiB
    const int t = threadIdx.x;
    const int nb0 = blockIdx.x * 64;

    // zero the accumulation tile (8192 words / 256 threads)
#pragma unroll
    for (int i = 0; i < 32; i++) lacc[t + i * 256] = 0.f;

    const int start = offsets[nb0];
    const int end = offsets[min(nb0 + 64, N)];
    __syncthreads();

    // ---- edge-stream phase ----
    const int g = t >> 4;        // 16-lane group id (edge slot)
    const int f = t & 15;        // feat lane: uint4 #f of the row
    const int len = end - start;
    const int gs = start + (int)(((long)len * g) >> 4);
    const int ge = start + (int)(((long)len * (g + 1)) >> 4);

    const uint4* hb = (const uint4*)h;   // 16 uint4 per 128-feat row

    float r[8];
    int cur = -1;
#pragma unroll
    for (int j = 0; j < 8; j++) r[j] = 0.f;

    for (int e = gs; e < ge; e += 4) {
        int2 ed[4];
        uint4 d[4];
#pragma unroll
        for (int u = 0; u < 4; u++) {
            const int ee = min(e + u, ge - 1);
            ed[u] = sorted_ed[ee];
            d[u] = hb[(long)ed[u].x * 16 + f];
        }
#pragma unroll
        for (int u = 0; u < 4; u++) {
            if (e + u < ge) {
                if (ed[u].y != cur) {
                    if (cur >= 0) {
                        const int dl = cur - nb0;
                        const int X = (dl & 7) << 2;
#pragma unroll
                        for (int j = 0; j < 8; j++)
                            atomicAdd(&lacc[dl * FEAT + ((f * 8 + j) ^ X)], r[j]);
                    }
                    cur = ed[u].y;
#pragma unroll
                    for (int j = 0; j < 8; j++) r[j] = 0.f;
                }
                r[0] += bf_lo(d[u].x); r[1] += bf_hi(d[u].x);
                r[2] += bf_lo(d[u].y); r[3] += bf_hi(d[u].y);
                r[4] += bf_lo(d[u].z); r[5] += bf_hi(d[u].z);
                r[6] += bf_lo(d[u].w); r[7] += bf_hi(d[u].w);
            }
        }
    }
    if (cur >= 0) {
        const int dl = cur - nb0;
        const int X = (dl & 7) << 2;
#pragma unroll
        for (int j = 0; j < 8; j++)
            atomicAdd(&lacc[dl * FEAT + ((f * 8 + j) ^ X)], r[j]);
    }
    __syncthreads();

    // ---- MFMA phase: wave w -> local nodes w*16 .. w*16+15 ----
    const int wave = t >> 6;
    const int lane = t & 63;
    const int quad = lane >> 4;
    const int l15 = lane & 15;
    const int nl = wave * 16 + l15;
    const int Xr = (nl & 7) << 2;

    short8 afrag[4];
#pragma unroll
    for (int kc = 0; kc < 4; kc++) {
        const int b0 = kc * 32 + quad * 8;
        const float4 a0 = *(const float4*)&lacc[nl * FEAT + (b0 ^ Xr)];
        const float4 a1 = *(const float4*)&lacc[nl * FEAT + ((b0 + 4) ^ Xr)];
        unsigned short fr[8];
        fr[0] = f2bf(a0.x); fr[1] = f2bf(a0.y); fr[2] = f2bf(a0.z); fr[3] = f2bf(a0.w);
        fr[4] = f2bf(a1.x); fr[5] = f2bf(a1.y); fr[6] = f2bf(a1.z); fr[7] = f2bf(a1.w);
        afrag[kc] = *(short8*)fr;
    }

    floatx4 cacc[8];
#pragma unroll
    for (int ct = 0; ct < 8; ct++) cacc[ct] = (floatx4){0.f, 0.f, 0.f, 0.f};
#pragma unroll
    for (int kc = 0; kc < 4; kc++) {
#pragma unroll
        for (int ct = 0; ct < 8; ct++) {
            const short8 b = *(const short8*)&bfW[((kc * 8 + ct) * 64 + lane) * 8];
            cacc[ct] = __builtin_amdgcn_mfma_f32_16x16x32_bf16(afrag[kc], b, cacc[ct], 0, 0, 0);
        }
    }

    // ---- epilogue: C/D layout col=ct*16+l15, row=quad*4+r, direct stores.
#pragma unroll
    for (int ct = 0; ct < 8; ct++) {
        const int col = ct * 16 + l15;
        const float bv = bias[col];
#pragma unroll
        for (int r4i = 0; r4i < 4; r4i++) {
            const int row = nb0 + wave * 16 + quad * 4 + r4i;
            if (row < N) {
                float v = cacc[ct][r4i] + bv;
                if (RELU) v = fmaxf(v, 0.f);
                if (OUT_BF16)
                    ((unsigned short*)out)[(long)row * FEAT + col] = f2bf(v);
                else
                    ((float*)out)[(long)row * FEAT + col] = v;
            }
        }
    }
}

// ===========================================================================
// Pipeline (bf16 payloads, fp32 accumulation):
//   counts=0; convert+hist+prep_w; scan; add_base(+scan2); permute(int2)
//   h1b = gather_gemm(xb, W1, b1, relu) -> bf16
//   out = gather_gemm(h1b, W2, b2)      -> fp32
// Linearity: segment_sum((hW)[src]) == (segment_sum h[src]) @ W.
// ===========================================================================
extern "C" void kernel_launch(void* const* d_in, const int* in_sizes, int n_in,
                              void* d_out, int out_size, void* d_ws, size_t ws_size,
                              hipStream_t stream) {
    const float* x  = (const float*)d_in[0];
    const int*   ei = (const int*)d_in[1];
    const float* W1 = (const float*)d_in[2];
    const float* b1 = (const float*)d_in[3];
    const float* W2 = (const float*)d_in[4];
    const float* b2 = (const float*)d_in[5];
    float* out = (float*)d_out;

    const int N = in_sizes[0] / FEAT;
    const int E = in_sizes[1] / 2;
    const int* src = ei;
    const int* dst = ei + E;

    // Workspace carve-up (~58 MB).
    unsigned short* xb   = (unsigned short*)d_ws;            // N*128 bf16
    unsigned short* h1b  = xb + (size_t)N * FEAT;            // N*128 bf16
    unsigned short* bfW1 = h1b + (size_t)N * FEAT;           // 16384
    unsigned short* bfW2 = bfW1 + 16384;                     // 16384
    int* counts    = (int*)(bfW2 + 16384);                   // [N]
    int* offsets   = counts + N;                             // [N+1]
    int* cursor    = offsets + N + 1;                        // [N]
    int* blocksums = cursor + N;                             // [<=128]
    int2* sorted_ed = (int2*)(blocksums + 128 + 1);          // [E] (8B align ok: offset even)

    const int NB = (N + 1023) / 1024;
    const int eb = (E + 255) / 256;
    const int nb = (N + 255) / 256;
    const long n4 = (long)N * FEAT / 4;
    const int chB = (int)((n4 + 255) / 256);

    // ---- CSR build + bf16 prep (+ concurrent W repack) ----
    hipMemsetAsync(counts, 0, (size_t)N * sizeof(int), stream);
    convert_hist_prep<<<chB + 2, 256, 0, stream>>>(x, xb, n4, dst, counts, E,
                                                   W1, W2, bfW1, bfW2, chB);
    scan_chunk<<<NB, 256, 0, stream>>>(counts, offsets, blocksums, N);
    add_base<<<nb, 256, 0, stream>>>(offsets, cursor, blocksums, N, E);
    permute_kernel<<<eb, 256, 0, stream>>>(src, dst, cursor, sorted_ed, E);

    const int fused_blocks = (N + 63) / 64;

    // ---- Layer 1 (bf16 out) / Layer 2 (fp32 out) ----
    gather_gemm<true, true><<<fused_blocks, 256, 0, stream>>>(
        xb, offsets, sorted_ed, bfW1, b1, h1b, N);
    gather_gemm<false, false><<<fused_blocks, 256, 0, stream>>>(
        h1b, offsets, sorted_ed, bfW2, b2, out, N);
}